// Round 1
// baseline (2066.195 us; speedup 1.0000x reference)
//
#include <hip/hip_runtime.h>

typedef unsigned short u16;
typedef unsigned int u32;
typedef __bf16 bf16x8 __attribute__((ext_vector_type(8)));
typedef float f32x4 __attribute__((ext_vector_type(4)));

// Problem constants (fixed by reference): B=4, T=8192, C=2048, H=16, dh=128, BLOCK=128
#define DIM_M 32768      // B*T
#define DIM_C 2048
#define DIM_3C 6144
#define N_HEAD 16
#define DH 128

__device__ __forceinline__ u16 f2bf(float f) {
  u32 x = __float_as_uint(f);
  u32 r = x + 0x7fffu + ((x >> 16) & 1u);  // RNE
  return (u16)(r >> 16);
}

__device__ __forceinline__ void async_copy16(const void* g, void* l) {
  __builtin_amdgcn_global_load_lds((const __attribute__((address_space(1))) u32*)g,
                                   (__attribute__((address_space(3))) u32*)l,
                                   16, 0, 0);
}

// raw barrier: no vmcnt drain (unlike __syncthreads), pinned for phase discipline
__device__ __forceinline__ void phase_bar() {
  asm volatile("" ::: "memory");
  __builtin_amdgcn_sched_barrier(0);
  __builtin_amdgcn_s_barrier();
  __builtin_amdgcn_sched_barrier(0);
  asm volatile("" ::: "memory");
}

// ---------------- fp32 -> bf16 elementwise convert (x) ----------------
__global__ __launch_bounds__(256) void cvt_f32_bf16(const float* __restrict__ in,
                                                    u16* __restrict__ out) {
  size_t i = ((size_t)blockIdx.x * 256 + threadIdx.x) * 4;
  float4 v = *(const float4*)(in + i);
  union { u16 s[4]; uint2 u; } o;
  o.s[0] = f2bf(v.x); o.s[1] = f2bf(v.y); o.s[2] = f2bf(v.z); o.s[3] = f2bf(v.w);
  *(uint2*)(out + i) = o.u;
}

// ------------- fp32 KxN -> bf16 NxK transpose-convert (weights) -------------
__global__ __launch_bounds__(256) void transpose_cvt(const float* __restrict__ W,
                                                     u16* __restrict__ Wt,
                                                     int K, int N) {
  __shared__ u16 t[32][33];
  int nb = blockIdx.x * 32, kb = blockIdx.y * 32;
  int r = threadIdx.x >> 5, c = threadIdx.x & 31;
#pragma unroll
  for (int i = 0; i < 4; ++i) {
    int rr = i * 8 + r;
    t[rr][c] = f2bf(W[(size_t)(kb + rr) * N + nb + c]);
  }
  __syncthreads();
#pragma unroll
  for (int i = 0; i < 4; ++i) {
    int rr = i * 8 + r;
    Wt[(size_t)(nb + rr) * K + kb + c] = t[c][rr];
  }
}

// ---------------- 256x256 8-phase bf16 GEMM, B^T input (both K-major) ----------------
// C[M,N] = A[M,K] * Bt[N,K]^T ; BM=BN=256, BK=64, 512 threads = 8 waves (2M x 4N),
// per-wave output 128x64 (8x4 fragments of 16x16). LDS 128 KiB double-buffered.
// LDS swizzle: 16B chunk index XOR (row&7) within each 128B row (conflict-free b128 reads);
// applied as pre-swizzled GLOBAL source + swizzled ds_read (global_load_lds dest is linear).
// Staging for K-tile kt+1 issued at phases 0-1 of kt; single vmcnt drain per K-tile via
// the boundary __syncthreads() (loads are then 3-4 phases old -> latency covered).
#define STAGE(OP, BUF, KOFF)                                                        \
  do {                                                                              \
    _Pragma("unroll") for (int l_ = 0; l_ < 4; ++l_)                                \
        async_copy16(g##OP + (size_t)l_ * 64 * K + (KOFF),                          \
                     &s##OP[BUF][(l_ * 8 + w) * 512]);                              \
  } while (0)

#define LDA_Q(QA)                                                                   \
  do {                                                                              \
    _Pragma("unroll") for (int f_ = 0; f_ < 4; ++f_)                                \
        _Pragma("unroll") for (int ks_ = 0; ks_ < 2; ++ks_) {                       \
      int r_ = WR + (QA) * 64 + f_ * 16 + ln15;                                     \
      a[f_][ks_] = *(const bf16x8*)&sAc[r_ * 64 + (((ks_ * 4 + quad) ^ (r_ & 7)) * 8)]; \
    }                                                                               \
  } while (0)

#define LDB_Q(QB)                                                                   \
  do {                                                                              \
    _Pragma("unroll") for (int f_ = 0; f_ < 2; ++f_)                                \
        _Pragma("unroll") for (int ks_ = 0; ks_ < 2; ++ks_) {                       \
      int r_ = WC + (QB) * 32 + f_ * 16 + ln15;                                     \
      b[f_][ks_] = *(const bf16x8*)&sBc[r_ * 64 + (((ks_ * 4 + quad) ^ (r_ & 7)) * 8)]; \
    }                                                                               \
  } while (0)

#define MMA_Q(QA, QB)                                                               \
  do {                                                                              \
    __builtin_amdgcn_s_setprio(1);                                                  \
    _Pragma("unroll") for (int ks_ = 0; ks_ < 2; ++ks_)                             \
        _Pragma("unroll") for (int f_ = 0; f_ < 4; ++f_)                            \
            _Pragma("unroll") for (int g_ = 0; g_ < 2; ++g_)                        \
                acc[(QA) * 4 + f_][(QB) * 2 + g_] =                                 \
        __builtin_amdgcn_mfma_f32_16x16x32_bf16(                                    \
            a[f_][ks_], b[g_][ks_], acc[(QA) * 4 + f_][(QB) * 2 + g_], 0, 0, 0);    \
    __builtin_amdgcn_s_setprio(0);                                                  \
  } while (0)

template <bool OUT_BF16>
__global__ __launch_bounds__(512, 2) void gemm256(const u16* __restrict__ A,
                                                  const u16* __restrict__ Bt,
                                                  void* __restrict__ Cv,
                                                  int M, int N, int K) {
  __shared__ u16 sA[2][256 * 64];
  __shared__ u16 sB[2][256 * 64];

  const int NT = N >> 8;
  int wg = blockIdx.x;
  {  // bijective XCD swizzle (grid % 8 == 0 for both call sites)
    const int cpx = gridDim.x >> 3;
    wg = (wg & 7) * cpx + (wg >> 3);
  }
  const int rowblk = (wg / NT) << 8;
  const int colblk = (wg % NT) << 8;

  const int tid = threadIdx.x;
  const int w = tid >> 6, lane = tid & 63;
  const int ln15 = lane & 15, quad = lane >> 4;
  const int WR = (w >> 2) << 7;  // 0 / 128
  const int WC = (w & 3) << 6;   // 0 / 64 / 128 / 192

  // staging geometry: load l of op X covers rows l*64 + w*8 + (lane>>3);
  // dest is linear (chunk = lane&7), so source chunk is pre-swizzled by row&7.
  const int srow = (w << 3) + (lane >> 3);
  const int scl = (lane & 7) ^ ((lane >> 3) & 7);
  const u16* gA = A + (size_t)(rowblk + srow) * K + scl * 8;
  const u16* gB = Bt + (size_t)(colblk + srow) * K + scl * 8;

  f32x4 acc[8][4] = {};
  bf16x8 a[4][2], b[2][2];
  const int KT = K >> 6;

  // prologue: stage K-tile 0 into buffer 0, drain, go
  STAGE(A, 0, 0);
  STAGE(B, 0, 0);
  __syncthreads();

  for (int kt = 0; kt < KT; ++kt) {
    const int cur = kt & 1, nxt = cur ^ 1;
    const u16* sAc = sA[cur];
    const u16* sBc = sB[cur];
    const size_t gk = (size_t)(kt + 1) * 64;
    const bool pf = (kt + 1) < KT;

    // phase 0: qa=0, qb=0 (stage next A early: 4 phases before needed)
    if (pf) STAGE(A, nxt, gk);
    LDA_Q(0);
    LDB_Q(0);
    phase_bar();
    MMA_Q(0, 0);
    phase_bar();
    // phase 1: qa=0, qb=1 (reuse A regs; stage next B)
    if (pf) STAGE(B, nxt, gk);
    LDB_Q(1);
    phase_bar();
    MMA_Q(0, 1);
    phase_bar();
    // phase 2: qa=1, qb=1 (reuse B regs)
    LDA_Q(1);
    phase_bar();
    MMA_Q(1, 1);
    phase_bar();
    // phase 3: qa=1, qb=0
    LDB_Q(0);
    phase_bar();
    MMA_Q(1, 0);
    // K-tile boundary: the ONE drain per tile (vmcnt(0)+lgkmcnt(0)+barrier).
    // Guarantees kt+1's staging (issued at ph0/ph1) is visible before any wave reads it,
    // and all reads of buf[cur] are done before kt+1 overwrites it.
    __syncthreads();
  }

  // epilogue: C/D layout col=lane&15, row=(lane>>4)*4+reg
#pragma unroll
  for (int fi = 0; fi < 8; ++fi) {
#pragma unroll
    for (int fj = 0; fj < 4; ++fj) {
      const float* ap = (const float*)&acc[fi][fj];
#pragma unroll
      for (int r = 0; r < 4; ++r) {
        int row = rowblk + WR + fi * 16 + quad * 4 + r;
        int col = colblk + WC + fj * 16 + ln15;
        if (OUT_BF16)
          ((u16*)Cv)[(size_t)row * N + col] = f2bf(ap[r]);
        else
          ((float*)Cv)[(size_t)row * N + col] = ap[r];
      }
    }
  }
}

// ---------------- block-local causal attention ----------------
// one workgroup per (b, seg, head): S=QK^T/sqrt(dh), causal softmax, O=PV
// LDS: buf0 = Q (later P), buf1 = K (later V^T); XOR-swizzled 16B chunks.
__global__ __launch_bounds__(256) void attn_block(const u16* __restrict__ qkv,
                                                  u16* __restrict__ y) {
  __shared__ u16 buf0[128 * 128];  // Q -> P
  __shared__ u16 buf1[128 * 128];  // K -> V^T
  const int h = blockIdx.x, n = blockIdx.y, b = blockIdx.z;
  const size_t rowbase = ((size_t)b * 8192 + (size_t)n * 128) * DIM_3C;
  const int qcol = h * DH, kcol = DIM_C + h * DH, vcol = 2 * DIM_C + h * DH;
  const int tid = threadIdx.x;
  const int wave = tid >> 6, lane = tid & 63;
  const int ln15 = lane & 15, quad = lane >> 4;
  const int r0 = wave * 32;

  // stage Q and K (swizzled: elem (row,d) at row*128 + ((d>>3)^(row&15))*8 + (d&7))
#pragma unroll
  for (int it = 0; it < 16; ++it) {
    int f = tid + it * 256;   // 0..4095
    int tk = f >> 5;          // 0..127
    int dg = f & 31;          // d = dg*4
    int off = tk * 128 + (((dg >> 1) ^ (tk & 15)) * 8) + (dg & 1) * 4;
    uint2 qv = *(const uint2*)(qkv + rowbase + (size_t)tk * DIM_3C + qcol + dg * 4);
    *(uint2*)(buf0 + off) = qv;
    uint2 kv = *(const uint2*)(qkv + rowbase + (size_t)tk * DIM_3C + kcol + dg * 4);
    *(uint2*)(buf1 + off) = kv;
  }
  __syncthreads();

  // S = Q K^T : wave handles rows r0..r0+31, all 128 cols
  f32x4 acc[2][8] = {};
#pragma unroll
  for (int ks = 0; ks < 4; ++ks) {
    bf16x8 aq[2], bk[8];
#pragma unroll
    for (int i = 0; i < 2; ++i) {
      int row = r0 + i * 16 + ln15;
      aq[i] = *(const bf16x8*)(buf0 + row * 128 + (((ks * 4 + quad) ^ (row & 15)) * 8));
    }
#pragma unroll
    for (int j = 0; j < 8; ++j) {
      int row = j * 16 + ln15;
      bk[j] = *(const bf16x8*)(buf1 + row * 128 + (((ks * 4 + quad) ^ (row & 15)) * 8));
    }
#pragma unroll
    for (int i = 0; i < 2; ++i)
#pragma unroll
      for (int j = 0; j < 8; ++j)
        acc[i][j] = __builtin_amdgcn_mfma_f32_16x16x32_bf16(aq[i], bk[j], acc[i][j], 0, 0, 0);
  }

  // masked softmax over full row (held across 8 j-tiles x 16 lanes of the quad)
  const float scale = 0.08838834764831845f;  // 1/sqrt(128)
  float lrow[2][4];
#pragma unroll
  for (int i = 0; i < 2; ++i) {
#pragma unroll
    for (int r = 0; r < 4; ++r) {
      int row = r0 + i * 16 + quad * 4 + r;
      float m = -1e30f;
#pragma unroll
      for (int j = 0; j < 8; ++j) {
        float* ap = (float*)&acc[i][j];
        int col = j * 16 + ln15;
        float s = ap[r] * scale;
        if (col > row) s = -1e30f;
        ap[r] = s;
        m = fmaxf(m, s);
      }
#pragma unroll
      for (int off = 1; off < 16; off <<= 1) m = fmaxf(m, __shfl_xor(m, off));
      float l = 0.f;
#pragma unroll
      for (int j = 0; j < 8; ++j) {
        float* ap = (float*)&acc[i][j];
        float p = __expf(ap[r] - m);
        ap[r] = p;
        l += p;
      }
#pragma unroll
      for (int off = 1; off < 16; off <<= 1) l += __shfl_xor(l, off);
      lrow[i][r] = l;
    }
  }
  __syncthreads();  // all waves done reading Q/K tiles

  // write P (bf16, swizzled) into buf0; stage V^T into buf1
#pragma unroll
  for (int i = 0; i < 2; ++i)
#pragma unroll
    for (int j = 0; j < 8; ++j) {
      const float* ap = (const float*)&acc[i][j];
#pragma unroll
      for (int r = 0; r < 4; ++r) {
        int row = r0 + i * 16 + quad * 4 + r;
        int col = j * 16 + ln15;
        buf0[row * 128 + (((col >> 3) ^ (row & 15)) * 8) + (col & 7)] = f2bf(ap[r]);
      }
    }
#pragma unroll
  for (int it = 0; it < 16; ++it) {
    int f = tid + it * 256;
    int tk = f >> 5;
    int dg = f & 31;
    uint2 vv = *(const uint2*)(qkv + rowbase + (size_t)tk * DIM_3C + vcol + dg * 4);
    union { u16 s[4]; uint2 u; } tmp;
    tmp.u = vv;
#pragma unroll
    for (int j = 0; j < 4; ++j) {
      int dd = dg * 4 + j;  // V^T element (dd, tk)
      buf1[dd * 128 + (((tk >> 3) ^ (dd & 15)) * 8) + (tk & 7)] = tmp.s[j];
    }
  }
  __syncthreads();

  // O = P V : rows r0..r0+31, d = 0..127
  f32x4 accO[2][8] = {};
#pragma unroll
  for (int ks = 0; ks < 4; ++ks) {
    bf16x8 ap[2], bv[8];
#pragma unroll
    for (int i = 0; i < 2; ++i) {
      int row = r0 + i * 16 + ln15;
      ap[i] = *(const bf16x8*)(buf0 + row * 128 + (((ks * 4 + quad) ^ (row & 15)) * 8));
    }
#pragma unroll
    for (int j = 0; j < 8; ++j) {
      int row = j * 16 + ln15;  // d-row of V^T
      bv[j] = *(const bf16x8*)(buf1 + row * 128 + (((ks * 4 + quad) ^ (row & 15)) * 8));
    }
#pragma unroll
    for (int i = 0; i < 2; ++i)
#pragma unroll
      for (int j = 0; j < 8; ++j)
        accO[i][j] = __builtin_amdgcn_mfma_f32_16x16x32_bf16(ap[i], bv[j], accO[i][j], 0, 0, 0);
  }

  u16* yb = y + ((size_t)b * 8192 + (size_t)n * 128) * DIM_C + h * DH;
#pragma unroll
  for (int i = 0; i < 2; ++i)
#pragma unroll
    for (int j = 0; j < 8; ++j) {
      const float* op = (const float*)&accO[i][j];
#pragma unroll
      for (int r = 0; r < 4; ++r) {
        int row = r0 + i * 16 + quad * 4 + r;
        int col = j * 16 + ln15;
        yb[(size_t)row * DIM_C + col] = f2bf(op[r] / lrow[i][r]);
      }
    }
}

extern "C" void kernel_launch(void* const* d_in, const int* in_sizes, int n_in,
                              void* d_out, int out_size, void* d_ws, size_t ws_size,
                              hipStream_t stream) {
  const float* x = (const float*)d_in[0];       // (4,8192,2048)
  const float* W_qkv = (const float*)d_in[1];   // (2048,6144)
  const float* W_proj = (const float*)d_in[2];  // (2048,2048)
  float* out = (float*)d_out;                   // (4,8192,2048) fp32

  char* ws = (char*)d_ws;
  // layout: [xb (aliased by yb) 128MiB][qkvb 384MiB][Wqt 24MiB][Wpt 8MiB] = 544MiB
  u16* xb = (u16*)ws;                                       // 32768*2048
  u16* yb = xb;                                             // alias: x dead after GEMM1
  u16* qkvb = (u16*)(ws + (size_t)134217728);               // 32768*6144
  u16* Wqt = (u16*)(ws + (size_t)134217728 + 402653184);    // 6144*2048
  u16* Wpt = Wqt + (size_t)6144 * 2048;                     // 2048*2048

  // 1. convert x -> bf16 (67.1M elems, 16.78M float4)
  cvt_f32_bf16<<<dim3(65536), dim3(256), 0, stream>>>(x, xb);
  // 2. weights -> bf16, transposed to N x K
  transpose_cvt<<<dim3(DIM_3C / 32, DIM_C / 32), dim3(256), 0, stream>>>(W_qkv, Wqt, DIM_C, DIM_3C);
  transpose_cvt<<<dim3(DIM_C / 32, DIM_C / 32), dim3(256), 0, stream>>>(W_proj, Wpt, DIM_C, DIM_C);
  // 3. qkv = x @ W_qkv  (bf16 out) — 256² 8-phase, grid 128x24 = 3072 (%8==0)
  gemm256<true><<<dim3((DIM_M / 256) * (DIM_3C / 256)), dim3(512), 0, stream>>>(
      xb, Wqt, (void*)qkvb, DIM_M, DIM_3C, DIM_C);
  // 4. block-local causal attention -> y (bf16)
  attn_block<<<dim3(N_HEAD, 64, 4), dim3(256), 0, stream>>>(qkvb, yb);
  // 5. out = y @ W_proj (fp32 out) — grid 128x8 = 1024 (%8==0)
  gemm256<false><<<dim3((DIM_M / 256) * (DIM_C / 256)), dim3(512), 0, stream>>>(
      yb, Wpt, (void*)out, DIM_M, DIM_C, DIM_C);
}

// Round 2
// 2059.805 us; speedup vs baseline: 1.0031x; 1.0031x over previous
//
#include <hip/hip_runtime.h>

typedef unsigned short u16;
typedef unsigned int u32;
typedef __bf16 bf16x8 __attribute__((ext_vector_type(8)));
typedef float f32x4 __attribute__((ext_vector_type(4)));

// Problem constants (fixed by reference): B=4, T=8192, C=2048, H=16, dh=128, BLOCK=128
#define DIM_M 32768      // B*T
#define DIM_C 2048
#define DIM_3C 6144
#define N_HEAD 16
#define DH 128

__device__ __forceinline__ u16 f2bf(float f) {
  u32 x = __float_as_uint(f);
  u32 r = x + 0x7fffu + ((x >> 16) & 1u);  // RNE
  return (u16)(r >> 16);
}

__device__ __forceinline__ void async_copy16(const void* g, void* l) {
  __builtin_amdgcn_global_load_lds((const __attribute__((address_space(1))) u32*)g,
                                   (__attribute__((address_space(3))) u32*)l,
                                   16, 0, 0);
}

// raw barrier: no vmcnt drain (unlike __syncthreads), pinned for phase discipline
__device__ __forceinline__ void phase_bar() {
  asm volatile("" ::: "memory");
  __builtin_amdgcn_sched_barrier(0);
  __builtin_amdgcn_s_barrier();
  __builtin_amdgcn_sched_barrier(0);
  asm volatile("" ::: "memory");
}

// ---------------- fp32 -> bf16 elementwise convert (x) ----------------
__global__ __launch_bounds__(256) void cvt_f32_bf16(const float* __restrict__ in,
                                                    u16* __restrict__ out) {
  size_t i = ((size_t)blockIdx.x * 256 + threadIdx.x) * 4;
  float4 v = *(const float4*)(in + i);
  union { u16 s[4]; uint2 u; } o;
  o.s[0] = f2bf(v.x); o.s[1] = f2bf(v.y); o.s[2] = f2bf(v.z); o.s[3] = f2bf(v.w);
  *(uint2*)(out + i) = o.u;
}

// ------------- fp32 KxN -> bf16 NxK transpose-convert (weights) -------------
__global__ __launch_bounds__(256) void transpose_cvt(const float* __restrict__ W,
                                                     u16* __restrict__ Wt,
                                                     int K, int N) {
  __shared__ u16 t[32][33];
  int nb = blockIdx.x * 32, kb = blockIdx.y * 32;
  int r = threadIdx.x >> 5, c = threadIdx.x & 31;
#pragma unroll
  for (int i = 0; i < 4; ++i) {
    int rr = i * 8 + r;
    t[rr][c] = f2bf(W[(size_t)(kb + rr) * N + nb + c]);
  }
  __syncthreads();
#pragma unroll
  for (int i = 0; i < 4; ++i) {
    int rr = i * 8 + r;
    Wt[(size_t)(nb + rr) * K + kb + c] = t[c][rr];
  }
}

// ------------- 256x256 bf16 GEMM, counted-vmcnt 4-deep ring (T2+T3+T4+T5) -------------
// C[M,N] = A[M,K] * Bt[N,K]^T ; BM=BN=256, BK=32, 512 threads = 8 waves (2M x 4N),
// per-wave output 128x64 = 8x4 fragments of 16x16, 32 MFMA per K-tile per wave.
// LDS: 4-buffer ring, 4 x (A 16KiB + B 16KiB) = 128 KiB. At BK=32 the row stride is
// 64B = 16 banks, so the natural layout is conflict-free for ds_read_b128 fragments
// (256 dword requests spread exactly 8 per bank) -> no swizzle, linear global_load_lds.
// Pipeline: prologue stages tiles 0..2; at tile t stage tile t+3 into buf[(t+3)&3]
// (= buf read during tile t-1; its readers completed before this tile's entry barrier).
// Entry wait: s_waitcnt vmcnt(8) -- waits ONLY the oldest 4 loads (tile t), leaving
// tiles t+1,t+2 (8 loads) in flight ACROSS the barrier. Never drains to 0 mid-loop
// (T4). Issue-to-wait distance ~3 tiles (~1000 cyc) covers HBM latency (~900 cyc).
#define STAGE(OP, BUF, TT)                                                   \
  do {                                                                       \
    _Pragma("unroll") for (int l_ = 0; l_ < 2; ++l_)                         \
        async_copy16(g##OP + (size_t)l_ * 128 * K + (size_t)(TT) * 32,       \
                     &s##OP[BUF][(l_ * 128 + w * 16) * 32]);                 \
  } while (0)

template <bool OUT_BF16>
__global__ __launch_bounds__(512, 2) void gemm256(const u16* __restrict__ A,
                                                  const u16* __restrict__ Bt,
                                                  void* __restrict__ Cv,
                                                  int M, int N, int K) {
  __shared__ u16 sA[4][256 * 32];
  __shared__ u16 sB[4][256 * 32];

  const int NT = N >> 8;
  int wg = blockIdx.x;
  {  // bijective XCD swizzle (grid % 8 == 0 for both call sites)
    const int cpx = gridDim.x >> 3;
    wg = (wg & 7) * cpx + (wg >> 3);
  }
  const int rowblk = (wg / NT) << 8;
  const int colblk = (wg % NT) << 8;

  const int tid = threadIdx.x;
  const int w = tid >> 6, lane = tid & 63;
  const int ln15 = lane & 15, quad = lane >> 4;
  const int WR = (w >> 2) << 7;  // 0 / 128
  const int WC = (w & 3) << 6;   // 0 / 64 / 128 / 192

  // staging geometry (per 16KiB half-tile = 2 loads/thread):
  // load l covers rows l*128 + w*16 + (lane>>2); 16B chunk = lane&3. LDS dest linear.
  const int srow = w * 16 + (lane >> 2);
  const int schunk = (lane & 3) * 8;  // u16 offset within a 32-elem row
  const u16* gA = A + (size_t)(rowblk + srow) * K + schunk;
  const u16* gB = Bt + (size_t)(colblk + srow) * K + schunk;

  f32x4 acc[8][4] = {};
  const int KT = K >> 5;  // 64 for K=2048

  // prologue: stage tiles 0,1,2 (12 loads in flight; per-tile issue order A0,A1,B0,B1)
#pragma unroll
  for (int pt = 0; pt < 3; ++pt) {
    STAGE(A, pt, pt);
    STAGE(B, pt, pt);
  }

  for (int t = 0; t < KT; ++t) {
    const int cur = t & 3;
    const u16* sAc = sA[cur];
    const u16* sBc = sB[cur];

    // entry: wait oldest tile only (counted, never 0 mid-loop), then align waves
    if (t <= KT - 3)      asm volatile("s_waitcnt vmcnt(8)" ::: "memory");
    else if (t == KT - 2) asm volatile("s_waitcnt vmcnt(4)" ::: "memory");
    else                  asm volatile("s_waitcnt vmcnt(0)" ::: "memory");
    phase_bar();

    // stage tile t+3 into the buffer freed at end of tile t-1
    if (t + 3 < KT) {
      STAGE(A, (t + 3) & 3, t + 3);
      STAGE(B, (t + 3) & 3, t + 3);
    }

    bf16x8 a[4], b[4];
    // phase 0: B frags (held across both phases) + A rows WR..WR+63
#pragma unroll
    for (int g = 0; g < 4; ++g) {
      int r = WC + g * 16 + ln15;
      b[g] = *(const bf16x8*)&sBc[r * 32 + quad * 8];
    }
#pragma unroll
    for (int f = 0; f < 4; ++f) {
      int r = WR + f * 16 + ln15;
      a[f] = *(const bf16x8*)&sAc[r * 32 + quad * 8];
    }
    phase_bar();
    __builtin_amdgcn_s_setprio(1);
#pragma unroll
    for (int f = 0; f < 4; ++f)
#pragma unroll
      for (int g = 0; g < 4; ++g)
        acc[f][g] = __builtin_amdgcn_mfma_f32_16x16x32_bf16(a[f], b[g], acc[f][g], 0, 0, 0);
    __builtin_amdgcn_s_setprio(0);

    // phase 1: A rows WR+64..WR+127, reuse B regs
    bf16x8 a2[4];
#pragma unroll
    for (int f = 0; f < 4; ++f) {
      int r = WR + 64 + f * 16 + ln15;
      a2[f] = *(const bf16x8*)&sAc[r * 32 + quad * 8];
    }
    phase_bar();
    __builtin_amdgcn_s_setprio(1);
#pragma unroll
    for (int f = 0; f < 4; ++f)
#pragma unroll
      for (int g = 0; g < 4; ++g)
        acc[4 + f][g] = __builtin_amdgcn_mfma_f32_16x16x32_bf16(a2[f], b[g], acc[4 + f][g], 0, 0, 0);
    __builtin_amdgcn_s_setprio(0);
    // next tile's entry barrier doubles as the end-of-tile fence: each wave's
    // lgkm waits (before the MFMAs above) precede it, so buf[cur] has no readers
    // when tile t+4's staging (issued after that barrier) overwrites it.
  }

  // epilogue: C/D layout col=lane&15, row=(lane>>4)*4+reg
#pragma unroll
  for (int fi = 0; fi < 8; ++fi) {
#pragma unroll
    for (int fj = 0; fj < 4; ++fj) {
      const float* ap = (const float*)&acc[fi][fj];
#pragma unroll
      for (int r = 0; r < 4; ++r) {
        int row = rowblk + WR + fi * 16 + quad * 4 + r;
        int col = colblk + WC + fj * 16 + ln15;
        if (OUT_BF16)
          ((u16*)Cv)[(size_t)row * N + col] = f2bf(ap[r]);
        else
          ((float*)Cv)[(size_t)row * N + col] = ap[r];
      }
    }
  }
}

// ---------------- block-local causal attention ----------------
// one workgroup per (b, seg, head): S=QK^T/sqrt(dh), causal softmax, O=PV
// LDS: buf0 = Q (later P), buf1 = K (later V^T); XOR-swizzled 16B chunks.
__global__ __launch_bounds__(256) void attn_block(const u16* __restrict__ qkv,
                                                  u16* __restrict__ y) {
  __shared__ u16 buf0[128 * 128];  // Q -> P
  __shared__ u16 buf1[128 * 128];  // K -> V^T
  const int h = blockIdx.x, n = blockIdx.y, b = blockIdx.z;
  const size_t rowbase = ((size_t)b * 8192 + (size_t)n * 128) * DIM_3C;
  const int qcol = h * DH, kcol = DIM_C + h * DH, vcol = 2 * DIM_C + h * DH;
  const int tid = threadIdx.x;
  const int wave = tid >> 6, lane = tid & 63;
  const int ln15 = lane & 15, quad = lane >> 4;
  const int r0 = wave * 32;

  // stage Q and K (swizzled: elem (row,d) at row*128 + ((d>>3)^(row&15))*8 + (d&7))
#pragma unroll
  for (int it = 0; it < 16; ++it) {
    int f = tid + it * 256;   // 0..4095
    int tk = f >> 5;          // 0..127
    int dg = f & 31;          // d = dg*4
    int off = tk * 128 + (((dg >> 1) ^ (tk & 15)) * 8) + (dg & 1) * 4;
    uint2 qv = *(const uint2*)(qkv + rowbase + (size_t)tk * DIM_3C + qcol + dg * 4);
    *(uint2*)(buf0 + off) = qv;
    uint2 kv = *(const uint2*)(qkv + rowbase + (size_t)tk * DIM_3C + kcol + dg * 4);
    *(uint2*)(buf1 + off) = kv;
  }
  __syncthreads();

  // S = Q K^T : wave handles rows r0..r0+31, all 128 cols
  f32x4 acc[2][8] = {};
#pragma unroll
  for (int ks = 0; ks < 4; ++ks) {
    bf16x8 aq[2], bk[8];
#pragma unroll
    for (int i = 0; i < 2; ++i) {
      int row = r0 + i * 16 + ln15;
      aq[i] = *(const bf16x8*)(buf0 + row * 128 + (((ks * 4 + quad) ^ (row & 15)) * 8));
    }
#pragma unroll
    for (int j = 0; j < 8; ++j) {
      int row = j * 16 + ln15;
      bk[j] = *(const bf16x8*)(buf1 + row * 128 + (((ks * 4 + quad) ^ (row & 15)) * 8));
    }
#pragma unroll
    for (int i = 0; i < 2; ++i)
#pragma unroll
      for (int j = 0; j < 8; ++j)
        acc[i][j] = __builtin_amdgcn_mfma_f32_16x16x32_bf16(aq[i], bk[j], acc[i][j], 0, 0, 0);
  }

  // masked softmax over full row (held across 8 j-tiles x 16 lanes of the quad)
  const float scale = 0.08838834764831845f;  // 1/sqrt(128)
  float lrow[2][4];
#pragma unroll
  for (int i = 0; i < 2; ++i) {
#pragma unroll
    for (int r = 0; r < 4; ++r) {
      int row = r0 + i * 16 + quad * 4 + r;
      float m = -1e30f;
#pragma unroll
      for (int j = 0; j < 8; ++j) {
        float* ap = (float*)&acc[i][j];
        int col = j * 16 + ln15;
        float s = ap[r] * scale;
        if (col > row) s = -1e30f;
        ap[r] = s;
        m = fmaxf(m, s);
      }
#pragma unroll
      for (int off = 1; off < 16; off <<= 1) m = fmaxf(m, __shfl_xor(m, off));
      float l = 0.f;
#pragma unroll
      for (int j = 0; j < 8; ++j) {
        float* ap = (float*)&acc[i][j];
        float p = __expf(ap[r] - m);
        ap[r] = p;
        l += p;
      }
#pragma unroll
      for (int off = 1; off < 16; off <<= 1) l += __shfl_xor(l, off);
      lrow[i][r] = l;
    }
  }
  __syncthreads();  // all waves done reading Q/K tiles

  // write P (bf16, swizzled) into buf0; stage V^T into buf1
#pragma unroll
  for (int i = 0; i < 2; ++i)
#pragma unroll
    for (int j = 0; j < 8; ++j) {
      const float* ap = (const float*)&acc[i][j];
#pragma unroll
      for (int r = 0; r < 4; ++r) {
        int row = r0 + i * 16 + quad * 4 + r;
        int col = j * 16 + ln15;
        buf0[row * 128 + (((col >> 3) ^ (row & 15)) * 8) + (col & 7)] = f2bf(ap[r]);
      }
    }
#pragma unroll
  for (int it = 0; it < 16; ++it) {
    int f = tid + it * 256;
    int tk = f >> 5;
    int dg = f & 31;
    uint2 vv = *(const uint2*)(qkv + rowbase + (size_t)tk * DIM_3C + vcol + dg * 4);
    union { u16 s[4]; uint2 u; } tmp;
    tmp.u = vv;
#pragma unroll
    for (int j = 0; j < 4; ++j) {
      int dd = dg * 4 + j;  // V^T element (dd, tk)
      buf1[dd * 128 + (((tk >> 3) ^ (dd & 15)) * 8) + (tk & 7)] = tmp.s[j];
    }
  }
  __syncthreads();

  // O = P V : rows r0..r0+31, d = 0..127
  f32x4 accO[2][8] = {};
#pragma unroll
  for (int ks = 0; ks < 4; ++ks) {
    bf16x8 ap[2], bv[8];
#pragma unroll
    for (int i = 0; i < 2; ++i) {
      int row = r0 + i * 16 + ln15;
      ap[i] = *(const bf16x8*)(buf0 + row * 128 + (((ks * 4 + quad) ^ (row & 15)) * 8));
    }
#pragma unroll
    for (int j = 0; j < 8; ++j) {
      int row = j * 16 + ln15;  // d-row of V^T
      bv[j] = *(const bf16x8*)(buf1 + row * 128 + (((ks * 4 + quad) ^ (row & 15)) * 8));
    }
#pragma unroll
    for (int i = 0; i < 2; ++i)
#pragma unroll
      for (int j = 0; j < 8; ++j)
        accO[i][j] = __builtin_amdgcn_mfma_f32_16x16x32_bf16(ap[i], bv[j], accO[i][j], 0, 0, 0);
  }

  u16* yb = y + ((size_t)b * 8192 + (size_t)n * 128) * DIM_C + h * DH;
#pragma unroll
  for (int i = 0; i < 2; ++i)
#pragma unroll
    for (int j = 0; j < 8; ++j) {
      const float* op = (const float*)&accO[i][j];
#pragma unroll
      for (int r = 0; r < 4; ++r) {
        int row = r0 + i * 16 + quad * 4 + r;
        int col = j * 16 + ln15;
        yb[(size_t)row * DIM_C + col] = f2bf(op[r] / lrow[i][r]);
      }
    }
}

extern "C" void kernel_launch(void* const* d_in, const int* in_sizes, int n_in,
                              void* d_out, int out_size, void* d_ws, size_t ws_size,
                              hipStream_t stream) {
  const float* x = (const float*)d_in[0];       // (4,8192,2048)
  const float* W_qkv = (const float*)d_in[1];   // (2048,6144)
  const float* W_proj = (const float*)d_in[2];  // (2048,2048)
  float* out = (float*)d_out;                   // (4,8192,2048) fp32

  char* ws = (char*)d_ws;
  // layout: [xb (aliased by yb) 128MiB][qkvb 384MiB][Wqt 24MiB][Wpt 8MiB] = 544MiB
  u16* xb = (u16*)ws;                                       // 32768*2048
  u16* yb = xb;                                             // alias: x dead after GEMM1
  u16* qkvb = (u16*)(ws + (size_t)134217728);               // 32768*6144
  u16* Wqt = (u16*)(ws + (size_t)134217728 + 402653184);    // 6144*2048
  u16* Wpt = Wqt + (size_t)6144 * 2048;                     // 2048*2048

  // 1. convert x -> bf16 (67.1M elems, 16.78M float4)
  cvt_f32_bf16<<<dim3(65536), dim3(256), 0, stream>>>(x, xb);
  // 2. weights -> bf16, transposed to N x K
  transpose_cvt<<<dim3(DIM_3C / 32, DIM_C / 32), dim3(256), 0, stream>>>(W_qkv, Wqt, DIM_C, DIM_3C);
  transpose_cvt<<<dim3(DIM_C / 32, DIM_C / 32), dim3(256), 0, stream>>>(W_proj, Wpt, DIM_C, DIM_C);
  // 3. qkv = x @ W_qkv  (bf16 out) — grid 128x24 = 3072 (%8==0)
  gemm256<true><<<dim3((DIM_M / 256) * (DIM_3C / 256)), dim3(512), 0, stream>>>(
      xb, Wqt, (void*)qkvb, DIM_M, DIM_3C, DIM_C);
  // 4. block-local causal attention -> y (bf16)
  attn_block<<<dim3(N_HEAD, 64, 4), dim3(256), 0, stream>>>(qkvb, yb);
  // 5. out = y @ W_proj (fp32 out) — grid 128x8 = 1024 (%8==0)
  gemm256<false><<<dim3((DIM_M / 256) * (DIM_C / 256)), dim3(512), 0, stream>>>(
      yb, Wpt, (void*)out, DIM_M, DIM_C, DIM_C);
}

// Round 3
// 2042.161 us; speedup vs baseline: 1.0118x; 1.0086x over previous
//
#include <hip/hip_runtime.h>

typedef unsigned short u16;
typedef unsigned int u32;
typedef __bf16 bf16x8 __attribute__((ext_vector_type(8)));
typedef float f32x4 __attribute__((ext_vector_type(4)));

// Problem constants (fixed by reference): B=4, T=8192, C=2048, H=16, dh=128, BLOCK=128
#define DIM_M 32768      // B*T
#define DIM_C 2048
#define DIM_3C 6144
#define N_HEAD 16
#define DH 128

__device__ __forceinline__ u16 f2bf(float f) {
  u32 x = __float_as_uint(f);
  u32 r = x + 0x7fffu + ((x >> 16) & 1u);  // RNE
  return (u16)(r >> 16);
}

__device__ __forceinline__ void async_copy16(const void* g, void* l) {
  __builtin_amdgcn_global_load_lds((const __attribute__((address_space(1))) u32*)g,
                                   (__attribute__((address_space(3))) u32*)l,
                                   16, 0, 0);
}

// raw barrier: no vmcnt drain (unlike __syncthreads), pinned for phase discipline
__device__ __forceinline__ void phase_bar() {
  asm volatile("" ::: "memory");
  __builtin_amdgcn_sched_barrier(0);
  __builtin_amdgcn_s_barrier();
  __builtin_amdgcn_sched_barrier(0);
  asm volatile("" ::: "memory");
}

// ---------------- fp32 -> bf16 elementwise convert (x) ----------------
__global__ __launch_bounds__(256) void cvt_f32_bf16(const float* __restrict__ in,
                                                    u16* __restrict__ out) {
  size_t i = ((size_t)blockIdx.x * 256 + threadIdx.x) * 4;
  float4 v = *(const float4*)(in + i);
  union { u16 s[4]; uint2 u; } o;
  o.s[0] = f2bf(v.x); o.s[1] = f2bf(v.y); o.s[2] = f2bf(v.z); o.s[3] = f2bf(v.w);
  *(uint2*)(out + i) = o.u;
}

// ------------- fp32 KxN -> bf16 NxK transpose-convert (weights) -------------
__global__ __launch_bounds__(256) void transpose_cvt(const float* __restrict__ W,
                                                     u16* __restrict__ Wt,
                                                     int K, int N) {
  __shared__ u16 t[32][33];
  int nb = blockIdx.x * 32, kb = blockIdx.y * 32;
  int r = threadIdx.x >> 5, c = threadIdx.x & 31;
#pragma unroll
  for (int i = 0; i < 4; ++i) {
    int rr = i * 8 + r;
    t[rr][c] = f2bf(W[(size_t)(kb + rr) * N + nb + c]);
  }
  __syncthreads();
#pragma unroll
  for (int i = 0; i < 4; ++i) {
    int rr = i * 8 + r;
    Wt[(size_t)(nb + rr) * K + kb + c] = t[c][rr];
  }
}

// ------------- 256x256 bf16 GEMM, counted-vmcnt 4-deep ring (T2+T3+T4+T5) -------------
// C[M,N] = A[M,K] * Bt[N,K]^T ; BM=BN=256, BK=32, 512 threads = 8 waves (2M x 4N),
// per-wave output 128x64 = 8x4 fragments of 16x16, 32 MFMA per K-tile per wave.
// LDS: 4-buffer ring, 4 x (A 16KiB + B 16KiB) = 128 KiB.
//
// LDS swizzle (fix for r2's 7.5e7 conflicts): HW resolves bank conflicts per 16-lane
// quarter-wave. Natural 64-B rows put a quarter-wave's b128 reads on 8 banks (4-way).
// Swizzle: 16-B chunk index c' = c ^ ((row>>1)&3). Then lanes (ln15=2m,2m+1) read
// chunk quad^(m&3) at bank offset 0/16 -> even lanes cover banks 0..15 twice, odd
// lanes 16..31 twice = 2/bank = minimum (conflict-free). Applied BOTH sides (rule 21):
// linear global_load_lds dest + pre-swizzled global source chunk (lane&3)^((lane>>3)&3)
// (identity (row>>1)&3 == (lane>>3)&3 holds for the staging geometry), and read-side
// chunk (quad ^ ((ln15>>1)&3)) (row bases are multiples of 16 -> lane-constant).
//
// Pipeline: prologue stages tiles 0..2; at tile t stage tile t+3 into buf[(t+3)&3]
// (= buf read during tile t-1; its readers completed before this tile's entry barrier).
// Entry wait: s_waitcnt vmcnt(8) -- waits ONLY the oldest 4 loads (tile t), leaving
// tiles t+1,t+2 (8 loads) in flight ACROSS the barrier. Never drains to 0 mid-loop
// (T4). Issue-to-wait distance ~3 tiles (~1000 cyc) covers HBM latency (~900 cyc).
#define STAGE(OP, BUF, TT)                                                   \
  do {                                                                       \
    _Pragma("unroll") for (int l_ = 0; l_ < 2; ++l_)                         \
        async_copy16(g##OP + (size_t)l_ * 128 * K + (size_t)(TT) * 32,       \
                     &s##OP[BUF][(l_ * 128 + w * 16) * 32]);                 \
  } while (0)

template <bool OUT_BF16>
__global__ __launch_bounds__(512, 2) void gemm256(const u16* __restrict__ A,
                                                  const u16* __restrict__ Bt,
                                                  void* __restrict__ Cv,
                                                  int M, int N, int K) {
  __shared__ u16 sA[4][256 * 32];
  __shared__ u16 sB[4][256 * 32];

  const int NT = N >> 8;
  int wg = blockIdx.x;
  {  // bijective XCD swizzle (grid % 8 == 0 for both call sites)
    const int cpx = gridDim.x >> 3;
    wg = (wg & 7) * cpx + (wg >> 3);
  }
  const int rowblk = (wg / NT) << 8;
  const int colblk = (wg % NT) << 8;

  const int tid = threadIdx.x;
  const int w = tid >> 6, lane = tid & 63;
  const int ln15 = lane & 15, quad = lane >> 4;
  const int WR = (w >> 2) << 7;  // 0 / 128
  const int WC = (w & 3) << 6;   // 0 / 64 / 128 / 192
  // read-side swizzled chunk offset (u16 units), lane-constant:
  const int rchunk = (quad ^ ((ln15 >> 1) & 3)) * 8;

  // staging geometry (per 16KiB half-tile = 2 loads/thread):
  // load l covers rows l*128 + w*16 + (lane>>2); LDS dest linear (chunk = lane&3),
  // so the GLOBAL source chunk is pre-swizzled: (lane&3) ^ ((lane>>3)&3).
  const int srow = w * 16 + (lane >> 2);
  const int schunk = ((lane & 3) ^ ((lane >> 3) & 3)) * 8;  // u16 offset in 32-elem row
  const u16* gA = A + (size_t)(rowblk + srow) * K + schunk;
  const u16* gB = Bt + (size_t)(colblk + srow) * K + schunk;

  f32x4 acc[8][4] = {};
  const int KT = K >> 5;  // 64 for K=2048

  // prologue: stage tiles 0,1,2 (12 loads in flight; per-tile issue order A0,A1,B0,B1)
#pragma unroll
  for (int pt = 0; pt < 3; ++pt) {
    STAGE(A, pt, pt);
    STAGE(B, pt, pt);
  }

  for (int t = 0; t < KT; ++t) {
    const int cur = t & 3;
    const u16* sAc = sA[cur];
    const u16* sBc = sB[cur];

    // entry: wait oldest tile only (counted, never 0 mid-loop), then align waves
    if (t <= KT - 3)      asm volatile("s_waitcnt vmcnt(8)" ::: "memory");
    else if (t == KT - 2) asm volatile("s_waitcnt vmcnt(4)" ::: "memory");
    else                  asm volatile("s_waitcnt vmcnt(0)" ::: "memory");
    phase_bar();

    // stage tile t+3 into the buffer freed at end of tile t-1
    if (t + 3 < KT) {
      STAGE(A, (t + 3) & 3, t + 3);
      STAGE(B, (t + 3) & 3, t + 3);
    }

    bf16x8 a[4], b[4];
    // phase 0: B frags (held across both phases) + A rows WR..WR+63
#pragma unroll
    for (int g = 0; g < 4; ++g) {
      int r = WC + g * 16 + ln15;
      b[g] = *(const bf16x8*)&sBc[r * 32 + rchunk];
    }
#pragma unroll
    for (int f = 0; f < 4; ++f) {
      int r = WR + f * 16 + ln15;
      a[f] = *(const bf16x8*)&sAc[r * 32 + rchunk];
    }
    phase_bar();
    __builtin_amdgcn_s_setprio(1);
#pragma unroll
    for (int f = 0; f < 4; ++f)
#pragma unroll
      for (int g = 0; g < 4; ++g)
        acc[f][g] = __builtin_amdgcn_mfma_f32_16x16x32_bf16(a[f], b[g], acc[f][g], 0, 0, 0);
    __builtin_amdgcn_s_setprio(0);

    // phase 1: A rows WR+64..WR+127, reuse B regs
    bf16x8 a2[4];
#pragma unroll
    for (int f = 0; f < 4; ++f) {
      int r = WR + 64 + f * 16 + ln15;
      a2[f] = *(const bf16x8*)&sAc[r * 32 + rchunk];
    }
    phase_bar();
    __builtin_amdgcn_s_setprio(1);
#pragma unroll
    for (int f = 0; f < 4; ++f)
#pragma unroll
      for (int g = 0; g < 4; ++g)
        acc[4 + f][g] = __builtin_amdgcn_mfma_f32_16x16x32_bf16(a2[f], b[g], acc[4 + f][g], 0, 0, 0);
    __builtin_amdgcn_s_setprio(0);
    // next tile's entry barrier doubles as the end-of-tile fence: each wave's
    // lgkm waits (before the MFMAs above) precede it, so buf[cur] has no readers
    // when tile t+4's staging (issued after that barrier) overwrites it.
  }

  // epilogue: C/D layout col=lane&15, row=(lane>>4)*4+reg
#pragma unroll
  for (int fi = 0; fi < 8; ++fi) {
#pragma unroll
    for (int fj = 0; fj < 4; ++fj) {
      const float* ap = (const float*)&acc[fi][fj];
#pragma unroll
      for (int r = 0; r < 4; ++r) {
        int row = rowblk + WR + fi * 16 + quad * 4 + r;
        int col = colblk + WC + fj * 16 + ln15;
        if (OUT_BF16)
          ((u16*)Cv)[(size_t)row * N + col] = f2bf(ap[r]);
        else
          ((float*)Cv)[(size_t)row * N + col] = ap[r];
      }
    }
  }
}

// ---------------- block-local causal attention ----------------
// one workgroup per (b, seg, head): S=QK^T/sqrt(dh), causal softmax, O=PV
// LDS: buf0 = Q (later P), buf1 = K (later V^T); XOR-swizzled 16B chunks.
__global__ __launch_bounds__(256) void attn_block(const u16* __restrict__ qkv,
                                                  u16* __restrict__ y) {
  __shared__ u16 buf0[128 * 128];  // Q -> P
  __shared__ u16 buf1[128 * 128];  // K -> V^T
  const int h = blockIdx.x, n = blockIdx.y, b = blockIdx.z;
  const size_t rowbase = ((size_t)b * 8192 + (size_t)n * 128) * DIM_3C;
  const int qcol = h * DH, kcol = DIM_C + h * DH, vcol = 2 * DIM_C + h * DH;
  const int tid = threadIdx.x;
  const int wave = tid >> 6, lane = tid & 63;
  const int ln15 = lane & 15, quad = lane >> 4;
  const int r0 = wave * 32;

  // stage Q and K (swizzled: elem (row,d) at row*128 + ((d>>3)^(row&15))*8 + (d&7))
#pragma unroll
  for (int it = 0; it < 16; ++it) {
    int f = tid + it * 256;   // 0..4095
    int tk = f >> 5;          // 0..127
    int dg = f & 31;          // d = dg*4
    int off = tk * 128 + (((dg >> 1) ^ (tk & 15)) * 8) + (dg & 1) * 4;
    uint2 qv = *(const uint2*)(qkv + rowbase + (size_t)tk * DIM_3C + qcol + dg * 4);
    *(uint2*)(buf0 + off) = qv;
    uint2 kv = *(const uint2*)(qkv + rowbase + (size_t)tk * DIM_3C + kcol + dg * 4);
    *(uint2*)(buf1 + off) = kv;
  }
  __syncthreads();

  // S = Q K^T : wave handles rows r0..r0+31, all 128 cols
  f32x4 acc[2][8] = {};
#pragma unroll
  for (int ks = 0; ks < 4; ++ks) {
    bf16x8 aq[2], bk[8];
#pragma unroll
    for (int i = 0; i < 2; ++i) {
      int row = r0 + i * 16 + ln15;
      aq[i] = *(const bf16x8*)(buf0 + row * 128 + (((ks * 4 + quad) ^ (row & 15)) * 8));
    }
#pragma unroll
    for (int j = 0; j < 8; ++j) {
      int row = j * 16 + ln15;
      bk[j] = *(const bf16x8*)(buf1 + row * 128 + (((ks * 4 + quad) ^ (row & 15)) * 8));
    }
#pragma unroll
    for (int i = 0; i < 2; ++i)
#pragma unroll
      for (int j = 0; j < 8; ++j)
        acc[i][j] = __builtin_amdgcn_mfma_f32_16x16x32_bf16(aq[i], bk[j], acc[i][j], 0, 0, 0);
  }

  // masked softmax over full row (held across 8 j-tiles x 16 lanes of the quad)
  const float scale = 0.08838834764831845f;  // 1/sqrt(128)
  float lrow[2][4];
#pragma unroll
  for (int i = 0; i < 2; ++i) {
#pragma unroll
    for (int r = 0; r < 4; ++r) {
      int row = r0 + i * 16 + quad * 4 + r;
      float m = -1e30f;
#pragma unroll
      for (int j = 0; j < 8; ++j) {
        float* ap = (float*)&acc[i][j];
        int col = j * 16 + ln15;
        float s = ap[r] * scale;
        if (col > row) s = -1e30f;
        ap[r] = s;
        m = fmaxf(m, s);
      }
#pragma unroll
      for (int off = 1; off < 16; off <<= 1) m = fmaxf(m, __shfl_xor(m, off));
      float l = 0.f;
#pragma unroll
      for (int j = 0; j < 8; ++j) {
        float* ap = (float*)&acc[i][j];
        float p = __expf(ap[r] - m);
        ap[r] = p;
        l += p;
      }
#pragma unroll
      for (int off = 1; off < 16; off <<= 1) l += __shfl_xor(l, off);
      lrow[i][r] = l;
    }
  }
  __syncthreads();  // all waves done reading Q/K tiles

  // write P (bf16, swizzled) into buf0; stage V^T into buf1
#pragma unroll
  for (int i = 0; i < 2; ++i)
#pragma unroll
    for (int j = 0; j < 8; ++j) {
      const float* ap = (const float*)&acc[i][j];
#pragma unroll
      for (int r = 0; r < 4; ++r) {
        int row = r0 + i * 16 + quad * 4 + r;
        int col = j * 16 + ln15;
        buf0[row * 128 + (((col >> 3) ^ (row & 15)) * 8) + (col & 7)] = f2bf(ap[r]);
      }
    }
#pragma unroll
  for (int it = 0; it < 16; ++it) {
    int f = tid + it * 256;
    int tk = f >> 5;
    int dg = f & 31;
    uint2 vv = *(const uint2*)(qkv + rowbase + (size_t)tk * DIM_3C + vcol + dg * 4);
    union { u16 s[4]; uint2 u; } tmp;
    tmp.u = vv;
#pragma unroll
    for (int j = 0; j < 4; ++j) {
      int dd = dg * 4 + j;  // V^T element (dd, tk)
      buf1[dd * 128 + (((tk >> 3) ^ (dd & 15)) * 8) + (tk & 7)] = tmp.s[j];
    }
  }
  __syncthreads();

  // O = P V : rows r0..r0+31, d = 0..127
  f32x4 accO[2][8] = {};
#pragma unroll
  for (int ks = 0; ks < 4; ++ks) {
    bf16x8 ap[2], bv[8];
#pragma unroll
    for (int i = 0; i < 2; ++i) {
      int row = r0 + i * 16 + ln15;
      ap[i] = *(const bf16x8*)(buf0 + row * 128 + (((ks * 4 + quad) ^ (row & 15)) * 8));
    }
#pragma unroll
    for (int j = 0; j < 8; ++j) {
      int row = j * 16 + ln15;  // d-row of V^T
      bv[j] = *(const bf16x8*)(buf1 + row * 128 + (((ks * 4 + quad) ^ (row & 15)) * 8));
    }
#pragma unroll
    for (int i = 0; i < 2; ++i)
#pragma unroll
      for (int j = 0; j < 8; ++j)
        accO[i][j] = __builtin_amdgcn_mfma_f32_16x16x32_bf16(ap[i], bv[j], accO[i][j], 0, 0, 0);
  }

  u16* yb = y + ((size_t)b * 8192 + (size_t)n * 128) * DIM_C + h * DH;
#pragma unroll
  for (int i = 0; i < 2; ++i)
#pragma unroll
    for (int j = 0; j < 8; ++j) {
      const float* op = (const float*)&accO[i][j];
#pragma unroll
      for (int r = 0; r < 4; ++r) {
        int row = r0 + i * 16 + quad * 4 + r;
        int col = j * 16 + ln15;
        yb[(size_t)row * DIM_C + col] = f2bf(op[r] / lrow[i][r]);
      }
    }
}

extern "C" void kernel_launch(void* const* d_in, const int* in_sizes, int n_in,
                              void* d_out, int out_size, void* d_ws, size_t ws_size,
                              hipStream_t stream) {
  const float* x = (const float*)d_in[0];       // (4,8192,2048)
  const float* W_qkv = (const float*)d_in[1];   // (2048,6144)
  const float* W_proj = (const float*)d_in[2];  // (2048,2048)
  float* out = (float*)d_out;                   // (4,8192,2048) fp32

  char* ws = (char*)d_ws;
  // layout: [xb (aliased by yb) 128MiB][qkvb 384MiB][Wqt 24MiB][Wpt 8MiB] = 544MiB
  u16* xb = (u16*)ws;                                       // 32768*2048
  u16* yb = xb;                                             // alias: x dead after GEMM1
  u16* qkvb = (u16*)(ws + (size_t)134217728);               // 32768*6144
  u16* Wqt = (u16*)(ws + (size_t)134217728 + 402653184);    // 6144*2048
  u16* Wpt = Wqt + (size_t)6144 * 2048;                     // 2048*2048

  // 1. convert x -> bf16 (67.1M elems, 16.78M float4)
  cvt_f32_bf16<<<dim3(65536), dim3(256), 0, stream>>>(x, xb);
  // 2. weights -> bf16, transposed to N x K
  transpose_cvt<<<dim3(DIM_3C / 32, DIM_C / 32), dim3(256), 0, stream>>>(W_qkv, Wqt, DIM_C, DIM_3C);
  transpose_cvt<<<dim3(DIM_C / 32, DIM_C / 32), dim3(256), 0, stream>>>(W_proj, Wpt, DIM_C, DIM_C);
  // 3. qkv = x @ W_qkv  (bf16 out) — grid 128x24 = 3072 (%8==0)
  gemm256<true><<<dim3((DIM_M / 256) * (DIM_3C / 256)), dim3(512), 0, stream>>>(
      xb, Wqt, (void*)qkvb, DIM_M, DIM_3C, DIM_C);
  // 4. block-local causal attention -> y (bf16)
  attn_block<<<dim3(N_HEAD, 64, 4), dim3(256), 0, stream>>>(qkvb, yb);
  // 5. out = y @ W_proj (fp32 out) — grid 128x8 = 1024 (%8==0)
  gemm256<false><<<dim3((DIM_M / 256) * (DIM_C / 256)), dim3(512), 0, stream>>>(
      yb, Wpt, (void*)out, DIM_M, DIM_C, DIM_C);
}